// Round 5
// baseline (496.907 us; speedup 1.0000x reference)
//
#include <hip/hip_runtime.h>
#include <math.h>

#define BATCH_N 16384

typedef _Float16 half8 __attribute__((ext_vector_type(8)));
typedef __fp16 h2 __attribute__((ext_vector_type(2)));   // cvt_pkrtz / fdot2 type
typedef float f32x4 __attribute__((ext_vector_type(4)));

// ---------------------------------------------------------------------------
// Monolith, 16 samples/block, 512 threads (8 waves), grid 1024.
// Exactly 4 blocks/CU by grid AND by LDS -> 32 waves/CU target (8/SIMD).
// Each wave owns 2 samples, processed sequentially (1-sample H1C buffer).
//
// LDS float-index map (8996 floats = 35984 B -> 4 blocks/CU):
//  [0,120)     C1P   conv1 w as f16 pairs [oc][ky][4]
//  [120,128)   BS1   conv1 bias (6 used)
//  [128,144)   BS2   conv2 bias
//  [144,240)   ROTM  12 gates x 8 (batch-uniform Rot matrices)
//  [240,368)   RXCS  rx cos[64] + sin[64]  (16 samples x 4 qubits)
//  [368,420)   CWB   clf w (40) + b (10)
//  [420,2276)  W2B   conv2 w f16 [16 oc][232] = 3712 halves = 1856 FLOATS
//              (R4 bug: H2A was placed at 1348, inside W2B -> clobbered oc 8-15)
//  [2276,4388) H2A   conv2 out f16 [16 s][264]  (264-stride: fc1 reads ~conflict-free)
//  [4388,8996) PW    per-wave H1C f16 [8 wv][144 units][8]  (1152 halves each)
//              fc1 phase: HS f16 [16 s][136] overlays PW (dead)
// ---------------------------------------------------------------------------
#define C1P_F  0
#define BS1_F  120
#define BS2_F  128
#define ROTM_F 144
#define RXCS_F 240
#define CWB_F  368
#define W2B_F  420
#define H2A_F  2276
#define PW_F   4388
#define LDS_FLOATS 8996

#define H1_WV_H   1152     // per-wave H1C halves (144 units x 8)
#define H2A_ROW_H 264      // H2A row stride (halves)
#define HS_ROW_H  136      // HS row stride (halves)

struct Row5 { h2 a0, a1, a2, s0, s1; };
static __device__ __forceinline__ Row5 packrow(float4 a, float2 c) {
    Row5 r;
    r.a0 = __builtin_amdgcn_cvt_pkrtz(a.x, a.y);
    r.a1 = __builtin_amdgcn_cvt_pkrtz(a.z, a.w);
    r.a2 = __builtin_amdgcn_cvt_pkrtz(c.x, c.y);
    r.s0 = __builtin_amdgcn_cvt_pkrtz(a.y, a.z);
    r.s1 = __builtin_amdgcn_cvt_pkrtz(a.w, c.x);
    return r;
}

__global__ __launch_bounds__(512, 8) void fused_model(
    const float* __restrict__ xg,
    const float* __restrict__ c1w, const float* __restrict__ c1b,
    const float* __restrict__ c2w, const float* __restrict__ c2b,
    const float* __restrict__ f1w, const float* __restrict__ f1b,
    const float* __restrict__ f2w, const float* __restrict__ f2b,
    const float* __restrict__ qw,  const float* __restrict__ cw,
    const float* __restrict__ cbias, float* __restrict__ out) {
    __shared__ float L[LDS_FLOATS];
    const int tid = threadIdx.x;
    const int b0 = blockIdx.x * 16;
    const int lane = tid & 63, wvi = tid >> 6;   // wvi 0..7
    const int ml = lane & 15, q = lane >> 4;

    _Float16* W2BH = (_Float16*)(L + W2B_F);
    _Float16* H2AH = (_Float16*)(L + H2A_F);
    _Float16* H1CH = (_Float16*)(L + PW_F) + wvi * H1_WV_H;
    _Float16* HSH  = (_Float16*)(L + PW_F);     // fc1 output overlay (PW dead)

    // ================= stage shared constants (one barrier) ================
    if (tid < 120) {  // conv1 weight f16 pairs
        const int oc = tid / 20, r = tid - oc * 20, ky = r >> 2, j = r & 3;
        const float* wb = c1w + oc * 25 + ky * 5;
        float lo, hi;
        if (j == 0)      { lo = wb[0]; hi = wb[1]; }
        else if (j == 1) { lo = wb[2]; hi = wb[3]; }
        else if (j == 2) { lo = wb[4]; hi = 0.f;   }
        else             { lo = 0.f;   hi = wb[4]; }
        ((h2*)&L[C1P_F])[tid] = __builtin_amdgcn_cvt_pkrtz(lo, hi);
    }
    if (tid < 6)  L[BS1_F + tid] = c1b[tid];
    if (tid < 16) L[BS2_F + tid] = c2b[tid];
    if (tid < 40) L[CWB_F + tid] = cw[tid];
    if (tid < 10) L[CWB_F + 40 + tid] = cbias[tid];
    if (tid < 12) {  // Rot gate matrices (batch-uniform)
        const float phi = qw[tid * 3 + 0];
        const float th  = qw[tid * 3 + 1];
        const float om  = qw[tid * 3 + 2];
        const float ct = cosf(0.5f * th), st = sinf(0.5f * th);
        const float ap = 0.5f * (phi + om), bm = 0.5f * (phi - om);
        const float ca = cosf(ap), sa = sinf(ap);
        const float cbm = cosf(bm), sbm = sinf(bm);
        float* R = &L[ROTM_F + tid * 8];
        R[0] =  ct * ca;  R[1] = -ct * sa;
        R[2] = -st * cbm; R[3] = -st * sbm;
        R[4] =  st * cbm; R[5] = -st * sbm;
        R[6] =  ct * ca;  R[7] =  ct * sa;
    }
#pragma unroll 1
    for (int i = tid; i < 3712; i += 512) {  // conv2 weights f16 [16][232]
        const int oc = i / 232, r = i - oc * 232;
        float v = 0.f;
        if (r < 200) {
            const int pix = r >> 3, ic = r & 7;
            if (ic < 6) v = c2w[oc * 150 + ic * 25 + pix];
        }
        W2BH[oc * 232 + r] = (_Float16)v;
    }
    __syncthreads();

    // ========== per-wave conv1+conv2, two samples sequentially =============
#pragma unroll 1
    for (int s = 0; s < 2; ++s) {
        const int smp = b0 + 2 * wvi + s;

        // ---- conv1 (dot2 f16, rolling 2-row global prefetch) -> H1C -----
        for (int t = lane; t < 144; t += 64) {
            const int py = t / 12, px = t - (t / 12) * 12;
            const float* xp = xg + (size_t)smp * 784 + py * 56 + px * 2;

            float acc[6][4];
#pragma unroll
            for (int oc = 0; oc < 6; oc++) {
                const float bv = L[BS1_F + oc];
                acc[oc][0] = bv; acc[oc][1] = bv; acc[oc][2] = bv; acc[oc][3] = bv;
            }

            Row5 P0 = packrow(*(const float4*)xp, *(const float2*)(xp + 4));
            Row5 P1 = packrow(*(const float4*)(xp + 28), *(const float2*)(xp + 32));
#pragma unroll
            for (int ky = 0; ky < 5; ky++) {
                float4 A; float2 C;
                if (ky < 4) {  // prefetch row ky+2 while computing on P0/P1
                    A = *(const float4*)(xp + (ky + 2) * 28);
                    C = *(const float2*)(xp + (ky + 2) * 28 + 4);
                }
#pragma unroll
                for (int oc = 0; oc < 6; oc++) {
                    union { uint4 v; h2 h[4]; } W;
                    W.v = ((const uint4*)&L[C1P_F])[oc * 5 + ky];
                    acc[oc][0] = __builtin_amdgcn_fdot2(P0.a0, W.h[0], acc[oc][0], false);
                    acc[oc][0] = __builtin_amdgcn_fdot2(P0.a1, W.h[1], acc[oc][0], false);
                    acc[oc][0] = __builtin_amdgcn_fdot2(P0.a2, W.h[2], acc[oc][0], false);
                    acc[oc][1] = __builtin_amdgcn_fdot2(P0.s0, W.h[0], acc[oc][1], false);
                    acc[oc][1] = __builtin_amdgcn_fdot2(P0.s1, W.h[1], acc[oc][1], false);
                    acc[oc][1] = __builtin_amdgcn_fdot2(P0.a2, W.h[3], acc[oc][1], false);
                    acc[oc][2] = __builtin_amdgcn_fdot2(P1.a0, W.h[0], acc[oc][2], false);
                    acc[oc][2] = __builtin_amdgcn_fdot2(P1.a1, W.h[1], acc[oc][2], false);
                    acc[oc][2] = __builtin_amdgcn_fdot2(P1.a2, W.h[2], acc[oc][2], false);
                    acc[oc][3] = __builtin_amdgcn_fdot2(P1.s0, W.h[0], acc[oc][3], false);
                    acc[oc][3] = __builtin_amdgcn_fdot2(P1.s1, W.h[1], acc[oc][3], false);
                    acc[oc][3] = __builtin_amdgcn_fdot2(P1.a2, W.h[3], acc[oc][3], false);
                }
                P0 = P1;
                if (ky < 4) P1 = packrow(A, C);
            }

            union { _Float16 h[8]; uint4 u; } O;
#pragma unroll
            for (int oc = 0; oc < 6; oc++) {
                const float m = fmaxf(fmaxf(acc[oc][0], acc[oc][1]), fmaxf(acc[oc][2], acc[oc][3]));
                O.h[oc] = (_Float16)fmaxf(m, 0.f);
            }
            O.h[6] = (_Float16)0.f; O.h[7] = (_Float16)0.f;
            *(uint4*)(H1CH + (py * 12 + px) * 8) = O.u;
        }
        __builtin_amdgcn_wave_barrier();

        // ---- conv2 via MFMA (b128 fragments) -> H2A row -----------------
        {
            f32x4 c2a[4];
#pragma unroll
            for (int b = 0; b < 4; b++) c2a[b] = (f32x4){0.f, 0.f, 0.f, 0.f};

#pragma unroll
            for (int ks = 0; ks < 7; ks++) {
                const half8 bfrag = *(const half8*)(W2BH + ml * 232 + ks * 32 + q * 8);
                int tp = ks * 4 + q; if (tp > 24) tp = 24;  // pad taps: B=0
                const int poff = (tp / 5) * 12 + (tp % 5);
#pragma unroll
                for (int t = 0; t < 4; t++) {
                    const int cp = t * 16 + ml;
                    const int unit = (cp >> 3) * 12 + (cp & 7) + poff;
                    const half8 afrag = *(const half8*)(H1CH + unit * 8);
                    c2a[t] = __builtin_amdgcn_mfma_f32_16x16x32_f16(afrag, bfrag, c2a[t], 0, 0, 0);
                }
            }

            // bias + pool + relu -> H2A row (2*wvi+s), own row: no race
            const float bv = L[BS2_F + ml];
#pragma unroll
            for (int t = 0; t < 4; t++) {
                const float c0 = c2a[t][0] + bv, c1 = c2a[t][1] + bv;
                const float c2 = c2a[t][2] + bv, c3 = c2a[t][3] + bv;
                float px0 = fmaxf(c0, c1), px1 = fmaxf(c2, c3);
                px0 = fmaxf(px0, __shfl_xor(px0, 32));
                px1 = fmaxf(px1, __shfl_xor(px1, 32));
                if (lane < 32) {
                    union { _Float16 h[2]; unsigned u; } P2;
                    P2.h[0] = (_Float16)fmaxf(px0, 0.f);
                    P2.h[1] = (_Float16)fmaxf(px1, 0.f);
                    *(unsigned*)(H2AH + (2 * wvi + s) * H2A_ROW_H + ml * 16 + t * 4 + (q & 1) * 2) = P2.u;
                }
            }
        }
        __builtin_amdgcn_wave_barrier();
    }
    __syncthreads();

    // ============ fc1 (256->120) via MFMA, M=16, 1 n-tile per wave =========
    {
        f32x4 fcC = (f32x4){0.f, 0.f, 0.f, 0.f};
        const int n = wvi * 16 + ml;               // neuron, 0..127
        const _Float16* h2p = H2AH + ml * H2A_ROW_H;  // A: sample = ml
#pragma unroll
        for (int ks = 0; ks < 8; ks++) {
            const half8 afrag = *(const half8*)(h2p + ks * 32 + q * 8);
            half8 bfrag;
            if (n < 120) {
                const float* wp = f1w + (size_t)n * 256 + ks * 32 + q * 8;
                const float4 u = *(const float4*)wp;
                const float4 v = *(const float4*)(wp + 4);
                bfrag[0] = (_Float16)u.x; bfrag[1] = (_Float16)u.y;
                bfrag[2] = (_Float16)u.z; bfrag[3] = (_Float16)u.w;
                bfrag[4] = (_Float16)v.x; bfrag[5] = (_Float16)v.y;
                bfrag[6] = (_Float16)v.z; bfrag[7] = (_Float16)v.w;
            } else {
#pragma unroll
                for (int j = 0; j < 8; j++) bfrag[j] = (_Float16)0.f;
            }
            fcC = __builtin_amdgcn_mfma_f32_16x16x32_f16(afrag, bfrag, fcC, 0, 0, 0);
        }
        // C: col=ml -> neuron n, row=q*4+rg -> sample
        if (n < 120) {
            const float bb = f1b[n];
#pragma unroll
            for (int rg = 0; rg < 4; rg++) {
                const int sr = q * 4 + rg;
                HSH[sr * HS_ROW_H + n] = (_Float16)fmaxf(fcC[rg] + bb, 0.f);
            }
        }
    }
    __syncthreads();

    // ====== fc2 (120->4) + pi*sigmoid, 256 threads (4-way split-K) =========
    if (tid < 256) {
        const int s = tid >> 4, m = (tid >> 2) & 3, part = tid & 3;
        float f = (part == 0) ? f2b[m] : 0.f;
#pragma unroll
        for (int i = 0; i < 4; ++i) {
            const int bblk = part + 4 * i;
            if (bblk < 15) {
                const half8 hv = *(const half8*)(HSH + s * HS_ROW_H + bblk * 8);
                const float* wp = f2w + m * 120 + bblk * 8;
                const float4 w0 = *(const float4*)wp;
                const float4 w1 = *(const float4*)(wp + 4);
                f = fmaf(w0.x, (float)hv[0], f); f = fmaf(w0.y, (float)hv[1], f);
                f = fmaf(w0.z, (float)hv[2], f); f = fmaf(w0.w, (float)hv[3], f);
                f = fmaf(w1.x, (float)hv[4], f); f = fmaf(w1.y, (float)hv[5], f);
                f = fmaf(w1.z, (float)hv[6], f); f = fmaf(w1.w, (float)hv[7], f);
            }
        }
        f += __shfl_xor(f, 1);
        f += __shfl_xor(f, 2);
        if (part == 0) {
            const float ang = 3.14159265358979323846f / (1.f + expf(-f));
            L[RXCS_F + s * 4 + m]      = cosf(0.5f * ang);
            L[RXCS_F + 64 + s * 4 + m] = sinf(0.5f * ang);
        }
    }
    __syncthreads();

    // ============ circuit: 16 samples x 16 amplitudes on 4 waves ===========
    if (tid < 256) {
        const int s = tid >> 4, a = tid & 15;
        float ar = (a == 0) ? 1.f : 0.f, ai = 0.f;

#pragma unroll
        for (int l = 0; l < 3; l++) {
#pragma unroll
            for (int w = 0; w < 4; w++) {
                const float* R = &L[ROTM_F + (l * 4 + w) * 8];
                const int mask = 8 >> w;
                const float pr = __shfl_xor(ar, mask);
                const float pi = __shfl_xor(ai, mask);
                const bool bit = (a & mask) != 0;
                const float lr = bit ? pr : ar, li = bit ? pi : ai;
                const float hr = bit ? ar : pr, hi = bit ? ai : pi;
                const float Ar = bit ? R[4] : R[0], Ai = bit ? R[5] : R[1];
                const float Br = bit ? R[6] : R[2], Bi = bit ? R[7] : R[3];
                ar = Ar * lr - Ai * li + Br * hr - Bi * hi;
                ai = Ar * li + Ai * lr + Br * hi + Bi * hr;
            }
#pragma unroll
            for (int w = 0; w < 4; w++) {
                const int mc = 8 >> w, mt = 8 >> ((w + 1) & 3);
                const float pr = __shfl_xor(ar, mt);
                const float pi = __shfl_xor(ai, mt);
                const bool ctrl = (a & mc) != 0;
                ar = ctrl ? pr : ar;
                ai = ctrl ? pi : ai;
            }
#pragma unroll
            for (int w = 0; w < 4; w++) {
                const int mask = 8 >> w;
                const float c  = L[RXCS_F + s * 4 + w];
                const float s2 = L[RXCS_F + 64 + s * 4 + w];
                const float pr = __shfl_xor(ar, mask);
                const float pi = __shfl_xor(ai, mask);
                const float nr = fmaf(c, ar, s2 * pi);
                const float ni = fmaf(c, ai, -s2 * pr);
                ar = nr; ai = ni;
            }
        }

        float v = ar * ar + ai * ai;
#pragma unroll
        for (int d = 1; d < 16; d <<= 1) {
            const float pv = __shfl_xor(v, d);
            v = (a & d) ? (pv - v) : (v + pv);
        }

        if (a < 10) {
            const int base = (tid & 63) & ~15;
            float lg = L[CWB_F + 40 + a];
#pragma unroll
            for (int w = 0; w < 4; w++) {
                const float zw = __shfl(v, base | (8 >> w));
                lg = fmaf(L[CWB_F + a * 4 + w], zw, lg);
            }
            out[(size_t)(b0 + s) * 10 + a] = lg;
        }
    }
}

// ---------------------------------------------------------------------------
extern "C" void kernel_launch(void* const* d_in, const int* in_sizes, int n_in,
                              void* d_out, int out_size, void* d_ws, size_t ws_size,
                              hipStream_t stream) {
    const float* x   = (const float*)d_in[0];
    const float* c1w = (const float*)d_in[1];
    const float* c1b = (const float*)d_in[2];
    const float* c2w = (const float*)d_in[3];
    const float* c2b = (const float*)d_in[4];
    const float* f1w = (const float*)d_in[5];
    const float* f1b = (const float*)d_in[6];
    const float* f2w = (const float*)d_in[7];
    const float* f2b = (const float*)d_in[8];
    const float* qw  = (const float*)d_in[9];
    const float* cw  = (const float*)d_in[10];
    const float* cb  = (const float*)d_in[11];
    float* out = (float*)d_out;

    fused_model<<<BATCH_N / 16, 512, 0, stream>>>(x, c1w, c1b, c2w, c2b,
                                                  f1w, f1b, f2w, f2b,
                                                  qw, cw, cb, out);
}

// Round 6
// 470.884 us; speedup vs baseline: 1.0553x; 1.0553x over previous
//
#include <hip/hip_runtime.h>
#include <math.h>

#define BATCH_N 16384

typedef _Float16 half8 __attribute__((ext_vector_type(8)));
typedef __fp16 h2 __attribute__((ext_vector_type(2)));   // cvt_pkrtz / fdot2 type
typedef float f32x4 __attribute__((ext_vector_type(4)));

// ---------------------------------------------------------------------------
// Monolith, 16 samples/block, 512 threads (8 waves), grid 1024.
// __launch_bounds__(512, 6): 85 regs/wave total budget -> ~65 arch VGPRs
// after MFMA AGPRs. (512,8) forced a 64-total budget -> 32 arch VGPRs ->
// conv1 spilled to scratch (R5: 1.39 GB HBM traffic, 417 us). 6 waves/EU
// -> 3 blocks/CU (24 waves/CU), still 1.5x the 4/SIMD of all prior rounds.
// Each wave owns 2 samples, processed sequentially (1-sample H1C buffer).
//
// LDS float-index map (8996 floats = 35984 B):
//  [0,120)     C1P   conv1 w as f16 pairs [oc][ky][4]
//  [120,128)   BS1   conv1 bias (6 used)
//  [128,144)   BS2   conv2 bias
//  [144,240)   ROTM  12 gates x 8 (batch-uniform Rot matrices)
//  [240,368)   RXCS  rx cos[64] + sin[64]  (16 samples x 4 qubits)
//  [368,420)   CWB   clf w (40) + b (10)
//  [420,2276)  W2B   conv2 w f16 [16 oc][232] = 3712 halves = 1856 floats
//  [2276,4388) H2A   conv2 out f16 [16 s][264]  (264-stride: fc1 reads ~conflict-free)
//  [4388,8996) PW    per-wave H1C f16 [8 wv][144 units][8]  (1152 halves each)
//              fc1 phase: HS f16 [16 s][136] overlays PW (dead)
// ---------------------------------------------------------------------------
#define C1P_F  0
#define BS1_F  120
#define BS2_F  128
#define ROTM_F 144
#define RXCS_F 240
#define CWB_F  368
#define W2B_F  420
#define H2A_F  2276
#define PW_F   4388
#define LDS_FLOATS 8996

#define H1_WV_H   1152     // per-wave H1C halves (144 units x 8)
#define H2A_ROW_H 264      // H2A row stride (halves)
#define HS_ROW_H  136      // HS row stride (halves)

struct Row5 { h2 a0, a1, a2, s0, s1; };
static __device__ __forceinline__ Row5 packrow(float4 a, float2 c) {
    Row5 r;
    r.a0 = __builtin_amdgcn_cvt_pkrtz(a.x, a.y);
    r.a1 = __builtin_amdgcn_cvt_pkrtz(a.z, a.w);
    r.a2 = __builtin_amdgcn_cvt_pkrtz(c.x, c.y);
    r.s0 = __builtin_amdgcn_cvt_pkrtz(a.y, a.z);
    r.s1 = __builtin_amdgcn_cvt_pkrtz(a.w, c.x);
    return r;
}

__global__ __launch_bounds__(512, 6) void fused_model(
    const float* __restrict__ xg,
    const float* __restrict__ c1w, const float* __restrict__ c1b,
    const float* __restrict__ c2w, const float* __restrict__ c2b,
    const float* __restrict__ f1w, const float* __restrict__ f1b,
    const float* __restrict__ f2w, const float* __restrict__ f2b,
    const float* __restrict__ qw,  const float* __restrict__ cw,
    const float* __restrict__ cbias, float* __restrict__ out) {
    __shared__ float L[LDS_FLOATS];
    const int tid = threadIdx.x;
    const int b0 = blockIdx.x * 16;
    const int lane = tid & 63, wvi = tid >> 6;   // wvi 0..7
    const int ml = lane & 15, q = lane >> 4;

    _Float16* W2BH = (_Float16*)(L + W2B_F);
    _Float16* H2AH = (_Float16*)(L + H2A_F);
    _Float16* H1CH = (_Float16*)(L + PW_F) + wvi * H1_WV_H;
    _Float16* HSH  = (_Float16*)(L + PW_F);     // fc1 output overlay (PW dead)

    // ================= stage shared constants (one barrier) ================
    if (tid < 120) {  // conv1 weight f16 pairs
        const int oc = tid / 20, r = tid - oc * 20, ky = r >> 2, j = r & 3;
        const float* wb = c1w + oc * 25 + ky * 5;
        float lo, hi;
        if (j == 0)      { lo = wb[0]; hi = wb[1]; }
        else if (j == 1) { lo = wb[2]; hi = wb[3]; }
        else if (j == 2) { lo = wb[4]; hi = 0.f;   }
        else             { lo = 0.f;   hi = wb[4]; }
        ((h2*)&L[C1P_F])[tid] = __builtin_amdgcn_cvt_pkrtz(lo, hi);
    }
    if (tid < 6)  L[BS1_F + tid] = c1b[tid];
    if (tid < 16) L[BS2_F + tid] = c2b[tid];
    if (tid < 40) L[CWB_F + tid] = cw[tid];
    if (tid < 10) L[CWB_F + 40 + tid] = cbias[tid];
    if (tid < 12) {  // Rot gate matrices (batch-uniform)
        const float phi = qw[tid * 3 + 0];
        const float th  = qw[tid * 3 + 1];
        const float om  = qw[tid * 3 + 2];
        const float ct = cosf(0.5f * th), st = sinf(0.5f * th);
        const float ap = 0.5f * (phi + om), bm = 0.5f * (phi - om);
        const float ca = cosf(ap), sa = sinf(ap);
        const float cbm = cosf(bm), sbm = sinf(bm);
        float* R = &L[ROTM_F + tid * 8];
        R[0] =  ct * ca;  R[1] = -ct * sa;
        R[2] = -st * cbm; R[3] = -st * sbm;
        R[4] =  st * cbm; R[5] = -st * sbm;
        R[6] =  ct * ca;  R[7] =  ct * sa;
    }
#pragma unroll 1
    for (int i = tid; i < 3712; i += 512) {  // conv2 weights f16 [16][232]
        const int oc = i / 232, r = i - oc * 232;
        float v = 0.f;
        if (r < 200) {
            const int pix = r >> 3, ic = r & 7;
            if (ic < 6) v = c2w[oc * 150 + ic * 25 + pix];
        }
        W2BH[oc * 232 + r] = (_Float16)v;
    }
    __syncthreads();

    // ========== per-wave conv1+conv2, two samples sequentially =============
#pragma unroll 1
    for (int s = 0; s < 2; ++s) {
        const int smp = b0 + 2 * wvi + s;

        // ---- conv1 (dot2 f16, rolling 2-row global prefetch) -> H1C -----
        for (int t = lane; t < 144; t += 64) {
            const int py = t / 12, px = t - (t / 12) * 12;
            const float* xp = xg + (size_t)smp * 784 + py * 56 + px * 2;

            float acc[6][4];
#pragma unroll
            for (int oc = 0; oc < 6; oc++) {
                const float bv = L[BS1_F + oc];
                acc[oc][0] = bv; acc[oc][1] = bv; acc[oc][2] = bv; acc[oc][3] = bv;
            }

            Row5 P0 = packrow(*(const float4*)xp, *(const float2*)(xp + 4));
            Row5 P1 = packrow(*(const float4*)(xp + 28), *(const float2*)(xp + 32));
#pragma unroll
            for (int ky = 0; ky < 5; ky++) {
                float4 A; float2 C;
                if (ky < 4) {  // prefetch row ky+2 while computing on P0/P1
                    A = *(const float4*)(xp + (ky + 2) * 28);
                    C = *(const float2*)(xp + (ky + 2) * 28 + 4);
                }
#pragma unroll
                for (int oc = 0; oc < 6; oc++) {
                    union { uint4 v; h2 h[4]; } W;
                    W.v = ((const uint4*)&L[C1P_F])[oc * 5 + ky];
                    acc[oc][0] = __builtin_amdgcn_fdot2(P0.a0, W.h[0], acc[oc][0], false);
                    acc[oc][0] = __builtin_amdgcn_fdot2(P0.a1, W.h[1], acc[oc][0], false);
                    acc[oc][0] = __builtin_amdgcn_fdot2(P0.a2, W.h[2], acc[oc][0], false);
                    acc[oc][1] = __builtin_amdgcn_fdot2(P0.s0, W.h[0], acc[oc][1], false);
                    acc[oc][1] = __builtin_amdgcn_fdot2(P0.s1, W.h[1], acc[oc][1], false);
                    acc[oc][1] = __builtin_amdgcn_fdot2(P0.a2, W.h[3], acc[oc][1], false);
                    acc[oc][2] = __builtin_amdgcn_fdot2(P1.a0, W.h[0], acc[oc][2], false);
                    acc[oc][2] = __builtin_amdgcn_fdot2(P1.a1, W.h[1], acc[oc][2], false);
                    acc[oc][2] = __builtin_amdgcn_fdot2(P1.a2, W.h[2], acc[oc][2], false);
                    acc[oc][3] = __builtin_amdgcn_fdot2(P1.s0, W.h[0], acc[oc][3], false);
                    acc[oc][3] = __builtin_amdgcn_fdot2(P1.s1, W.h[1], acc[oc][3], false);
                    acc[oc][3] = __builtin_amdgcn_fdot2(P1.a2, W.h[3], acc[oc][3], false);
                }
                P0 = P1;
                if (ky < 4) P1 = packrow(A, C);
            }

            union { _Float16 h[8]; uint4 u; } O;
#pragma unroll
            for (int oc = 0; oc < 6; oc++) {
                const float m = fmaxf(fmaxf(acc[oc][0], acc[oc][1]), fmaxf(acc[oc][2], acc[oc][3]));
                O.h[oc] = (_Float16)fmaxf(m, 0.f);
            }
            O.h[6] = (_Float16)0.f; O.h[7] = (_Float16)0.f;
            *(uint4*)(H1CH + (py * 12 + px) * 8) = O.u;
        }
        __builtin_amdgcn_wave_barrier();

        // ---- conv2 via MFMA (b128 fragments) -> H2A row -----------------
        {
            f32x4 c2a[4];
#pragma unroll
            for (int b = 0; b < 4; b++) c2a[b] = (f32x4){0.f, 0.f, 0.f, 0.f};

#pragma unroll
            for (int ks = 0; ks < 7; ks++) {
                const half8 bfrag = *(const half8*)(W2BH + ml * 232 + ks * 32 + q * 8);
                int tp = ks * 4 + q; if (tp > 24) tp = 24;  // pad taps: B=0
                const int poff = (tp / 5) * 12 + (tp % 5);
#pragma unroll
                for (int t = 0; t < 4; t++) {
                    const int cp = t * 16 + ml;
                    const int unit = (cp >> 3) * 12 + (cp & 7) + poff;
                    const half8 afrag = *(const half8*)(H1CH + unit * 8);
                    c2a[t] = __builtin_amdgcn_mfma_f32_16x16x32_f16(afrag, bfrag, c2a[t], 0, 0, 0);
                }
            }

            // bias + pool + relu -> H2A row (2*wvi+s), own row: no race
            const float bv = L[BS2_F + ml];
#pragma unroll
            for (int t = 0; t < 4; t++) {
                const float c0 = c2a[t][0] + bv, c1 = c2a[t][1] + bv;
                const float c2 = c2a[t][2] + bv, c3 = c2a[t][3] + bv;
                float px0 = fmaxf(c0, c1), px1 = fmaxf(c2, c3);
                px0 = fmaxf(px0, __shfl_xor(px0, 32));
                px1 = fmaxf(px1, __shfl_xor(px1, 32));
                if (lane < 32) {
                    union { _Float16 h[2]; unsigned u; } P2;
                    P2.h[0] = (_Float16)fmaxf(px0, 0.f);
                    P2.h[1] = (_Float16)fmaxf(px1, 0.f);
                    *(unsigned*)(H2AH + (2 * wvi + s) * H2A_ROW_H + ml * 16 + t * 4 + (q & 1) * 2) = P2.u;
                }
            }
        }
        __builtin_amdgcn_wave_barrier();
    }
    __syncthreads();

    // ============ fc1 (256->120) via MFMA, M=16, 1 n-tile per wave =========
    {
        f32x4 fcC = (f32x4){0.f, 0.f, 0.f, 0.f};
        const int n = wvi * 16 + ml;               // neuron, 0..127
        const _Float16* h2p = H2AH + ml * H2A_ROW_H;  // A: sample = ml
#pragma unroll
        for (int ks = 0; ks < 8; ks++) {
            const half8 afrag = *(const half8*)(h2p + ks * 32 + q * 8);
            half8 bfrag;
            if (n < 120) {
                const float* wp = f1w + (size_t)n * 256 + ks * 32 + q * 8;
                const float4 u = *(const float4*)wp;
                const float4 v = *(const float4*)(wp + 4);
                bfrag[0] = (_Float16)u.x; bfrag[1] = (_Float16)u.y;
                bfrag[2] = (_Float16)u.z; bfrag[3] = (_Float16)u.w;
                bfrag[4] = (_Float16)v.x; bfrag[5] = (_Float16)v.y;
                bfrag[6] = (_Float16)v.z; bfrag[7] = (_Float16)v.w;
            } else {
#pragma unroll
                for (int j = 0; j < 8; j++) bfrag[j] = (_Float16)0.f;
            }
            fcC = __builtin_amdgcn_mfma_f32_16x16x32_f16(afrag, bfrag, fcC, 0, 0, 0);
        }
        // C: col=ml -> neuron n, row=q*4+rg -> sample
        if (n < 120) {
            const float bb = f1b[n];
#pragma unroll
            for (int rg = 0; rg < 4; rg++) {
                const int sr = q * 4 + rg;
                HSH[sr * HS_ROW_H + n] = (_Float16)fmaxf(fcC[rg] + bb, 0.f);
            }
        }
    }
    __syncthreads();

    // ====== fc2 (120->4) + pi*sigmoid, 256 threads (4-way split-K) =========
    if (tid < 256) {
        const int s = tid >> 4, m = (tid >> 2) & 3, part = tid & 3;
        float f = (part == 0) ? f2b[m] : 0.f;
#pragma unroll
        for (int i = 0; i < 4; ++i) {
            const int bblk = part + 4 * i;
            if (bblk < 15) {
                const half8 hv = *(const half8*)(HSH + s * HS_ROW_H + bblk * 8);
                const float* wp = f2w + m * 120 + bblk * 8;
                const float4 w0 = *(const float4*)wp;
                const float4 w1 = *(const float4*)(wp + 4);
                f = fmaf(w0.x, (float)hv[0], f); f = fmaf(w0.y, (float)hv[1], f);
                f = fmaf(w0.z, (float)hv[2], f); f = fmaf(w0.w, (float)hv[3], f);
                f = fmaf(w1.x, (float)hv[4], f); f = fmaf(w1.y, (float)hv[5], f);
                f = fmaf(w1.z, (float)hv[6], f); f = fmaf(w1.w, (float)hv[7], f);
            }
        }
        f += __shfl_xor(f, 1);
        f += __shfl_xor(f, 2);
        if (part == 0) {
            const float ang = 3.14159265358979323846f / (1.f + expf(-f));
            L[RXCS_F + s * 4 + m]      = cosf(0.5f * ang);
            L[RXCS_F + 64 + s * 4 + m] = sinf(0.5f * ang);
        }
    }
    __syncthreads();

    // ============ circuit: 16 samples x 16 amplitudes on 4 waves ===========
    if (tid < 256) {
        const int s = tid >> 4, a = tid & 15;
        float ar = (a == 0) ? 1.f : 0.f, ai = 0.f;

#pragma unroll
        for (int l = 0; l < 3; l++) {
#pragma unroll
            for (int w = 0; w < 4; w++) {
                const float* R = &L[ROTM_F + (l * 4 + w) * 8];
                const int mask = 8 >> w;
                const float pr = __shfl_xor(ar, mask);
                const float pi = __shfl_xor(ai, mask);
                const bool bit = (a & mask) != 0;
                const float lr = bit ? pr : ar, li = bit ? pi : ai;
                const float hr = bit ? ar : pr, hi = bit ? ai : pi;
                const float Ar = bit ? R[4] : R[0], Ai = bit ? R[5] : R[1];
                const float Br = bit ? R[6] : R[2], Bi = bit ? R[7] : R[3];
                ar = Ar * lr - Ai * li + Br * hr - Bi * hi;
                ai = Ar * li + Ai * lr + Br * hi + Bi * hr;
            }
#pragma unroll
            for (int w = 0; w < 4; w++) {
                const int mc = 8 >> w, mt = 8 >> ((w + 1) & 3);
                const float pr = __shfl_xor(ar, mt);
                const float pi = __shfl_xor(ai, mt);
                const bool ctrl = (a & mc) != 0;
                ar = ctrl ? pr : ar;
                ai = ctrl ? pi : ai;
            }
#pragma unroll
            for (int w = 0; w < 4; w++) {
                const int mask = 8 >> w;
                const float c  = L[RXCS_F + s * 4 + w];
                const float s2 = L[RXCS_F + 64 + s * 4 + w];
                const float pr = __shfl_xor(ar, mask);
                const float pi = __shfl_xor(ai, mask);
                const float nr = fmaf(c, ar, s2 * pi);
                const float ni = fmaf(c, ai, -s2 * pr);
                ar = nr; ai = ni;
            }
        }

        float v = ar * ar + ai * ai;
#pragma unroll
        for (int d = 1; d < 16; d <<= 1) {
            const float pv = __shfl_xor(v, d);
            v = (a & d) ? (pv - v) : (v + pv);
        }

        if (a < 10) {
            const int base = (tid & 63) & ~15;
            float lg = L[CWB_F + 40 + a];
#pragma unroll
            for (int w = 0; w < 4; w++) {
                const float zw = __shfl(v, base | (8 >> w));
                lg = fmaf(L[CWB_F + a * 4 + w], zw, lg);
            }
            out[(size_t)(b0 + s) * 10 + a] = lg;
        }
    }
}

// ---------------------------------------------------------------------------
extern "C" void kernel_launch(void* const* d_in, const int* in_sizes, int n_in,
                              void* d_out, int out_size, void* d_ws, size_t ws_size,
                              hipStream_t stream) {
    const float* x   = (const float*)d_in[0];
    const float* c1w = (const float*)d_in[1];
    const float* c1b = (const float*)d_in[2];
    const float* c2w = (const float*)d_in[3];
    const float* c2b = (const float*)d_in[4];
    const float* f1w = (const float*)d_in[5];
    const float* f1b = (const float*)d_in[6];
    const float* f2w = (const float*)d_in[7];
    const float* f2b = (const float*)d_in[8];
    const float* qw  = (const float*)d_in[9];
    const float* cw  = (const float*)d_in[10];
    const float* cb  = (const float*)d_in[11];
    float* out = (float*)d_out;

    fused_model<<<BATCH_N / 16, 512, 0, stream>>>(x, c1w, c1b, c2w, c2b,
                                                  f1w, f1b, f2w, f2b,
                                                  qw, cw, cb, out);
}

// Round 7
// 169.104 us; speedup vs baseline: 2.9385x; 2.7846x over previous
//
#include <hip/hip_runtime.h>
#include <math.h>

#define BATCH_N 16384

typedef _Float16 half8 __attribute__((ext_vector_type(8)));
typedef __fp16 h2 __attribute__((ext_vector_type(2)));   // cvt_pkrtz / fdot2 type
typedef float f32x4 __attribute__((ext_vector_type(4)));

// ---------------------------------------------------------------------------
// Monolith, 16 samples/block (grid 1024), 256 threads (4 waves), 4 blocks/CU.
// Theory: conv1's per-unit-iteration LDS weight re-reads (30 x ds_read_b128)
// saturate the per-CU LDS pipe (VALUBusy pinned ~52% across R0/R2/R3).
// Fix: hoist conv1 weights to VGPRs, two oc-passes (0-3, 4-5) to fit the
// 128-reg/wave budget at 4 waves/EU; w4 terms via f32 fmaf with w4 read
// from GLOBAL (uniform -> scalar cache, no LDS). Each wave: 4 samples seq.
//
// LDS float-index map (6692 floats = 26768 B):
//  [0,120)     C1P   conv1 w as f16 pairs [oc][ky][4]  (staging for reg-hoist)
//  [120,128)   BS1   conv1 bias (6 used)
//  [128,144)   BS2   conv2 bias
//  [144,240)   ROTM  12 gates x 8 (batch-uniform Rot matrices)
//  [240,368)   RXCS  rx cos[64] + sin[64]  (16 samples x 4 qubits)
//  [368,420)   CWB   clf w (40) + b (10)
//  [420,2276)  W2B   conv2 w f16 [16 oc][232] = 3712 halves = 1856 floats
//  [2276,4388) H2A   conv2 out f16 [16 s][264]
//  [4388,6692) PW    per-wave H1C f16 [4 wv][144 units][8] (1152 halves each)
//              fc1 phase: HS f16 [16 s][136] overlays PW (dead)
// ---------------------------------------------------------------------------
#define C1P_F  0
#define BS1_F  120
#define BS2_F  128
#define ROTM_F 144
#define RXCS_F 240
#define CWB_F  368
#define W2B_F  420
#define H2A_F  2276
#define PW_F   4388
#define LDS_FLOATS 6692

#define H1_WV_H   1152     // per-wave H1C halves (144 units x 8)
#define H2A_ROW_H 264      // H2A row stride (halves)
#define HS_ROW_H  136      // HS row stride (halves)

struct Row6 { h2 a0, a1, s0, s1; float cx, cy; };
static __device__ __forceinline__ Row6 packrow6(float4 a, float2 c) {
    Row6 r;
    r.a0 = __builtin_amdgcn_cvt_pkrtz(a.x, a.y);   // (x0,x1)
    r.a1 = __builtin_amdgcn_cvt_pkrtz(a.z, a.w);   // (x2,x3)
    r.s0 = __builtin_amdgcn_cvt_pkrtz(a.y, a.z);   // (x1,x2)
    r.s1 = __builtin_amdgcn_cvt_pkrtz(a.w, c.x);   // (x3,x4)
    r.cx = c.x; r.cy = c.y;                        // x4, x5 (f32)
    return r;
}

// One conv1 pass over NOC output channels starting at ocb.
// Weights held in registers across the whole unit loop; LDS touched only for
// the one-time b64 weight fetch and the H1C result writes.
template<int NOC>
static __device__ __forceinline__ void conv1_pass(
    const int ocb, const float* __restrict__ xbase,
    const float* __restrict__ c1w, const h2* __restrict__ C1Ph,
    const float* __restrict__ BS1p, _Float16* __restrict__ H1CH,
    const int lane) {
    uint2 wh[NOC][5];     // packed (w0,w1),(w2,w3) per (oc,ky)
    float w4[NOC][5];     // w4 as f32 (global read, uniform -> s-cache)
#pragma unroll
    for (int oi = 0; oi < NOC; ++oi)
#pragma unroll
        for (int ky = 0; ky < 5; ++ky) {
            wh[oi][ky] = *(const uint2*)&C1Ph[(ocb + oi) * 20 + ky * 4];
            w4[oi][ky] = c1w[(ocb + oi) * 25 + ky * 5 + 4];
        }

    for (int t = lane; t < 144; t += 64) {
        const int py = t / 12, px = t - (t / 12) * 12;
        const float* xp = xbase + py * 56 + px * 2;

        float acc[NOC][4];
#pragma unroll
        for (int oi = 0; oi < NOC; ++oi) {
            const float bv = BS1p[ocb + oi];
            acc[oi][0] = bv; acc[oi][1] = bv; acc[oi][2] = bv; acc[oi][3] = bv;
        }

        Row6 R0 = packrow6(*(const float4*)xp, *(const float2*)(xp + 4));
        Row6 R1 = packrow6(*(const float4*)(xp + 28), *(const float2*)(xp + 32));
#pragma unroll
        for (int ky = 0; ky < 5; ++ky) {
            float4 A; float2 C;
            if (ky < 4) {  // prefetch row ky+2 while computing on R0/R1
                A = *(const float4*)(xp + (ky + 2) * 28);
                C = *(const float2*)(xp + (ky + 2) * 28 + 4);
            }
#pragma unroll
            for (int oi = 0; oi < NOC; ++oi) {
                union { uint2 v; h2 h[2]; } W; W.v = wh[oi][ky];
                const float wv4 = w4[oi][ky];
                acc[oi][0] = __builtin_amdgcn_fdot2(R0.a0, W.h[0], acc[oi][0], false);
                acc[oi][0] = __builtin_amdgcn_fdot2(R0.a1, W.h[1], acc[oi][0], false);
                acc[oi][0] = fmaf(wv4, R0.cx, acc[oi][0]);
                acc[oi][1] = __builtin_amdgcn_fdot2(R0.s0, W.h[0], acc[oi][1], false);
                acc[oi][1] = __builtin_amdgcn_fdot2(R0.s1, W.h[1], acc[oi][1], false);
                acc[oi][1] = fmaf(wv4, R0.cy, acc[oi][1]);
                acc[oi][2] = __builtin_amdgcn_fdot2(R1.a0, W.h[0], acc[oi][2], false);
                acc[oi][2] = __builtin_amdgcn_fdot2(R1.a1, W.h[1], acc[oi][2], false);
                acc[oi][2] = fmaf(wv4, R1.cx, acc[oi][2]);
                acc[oi][3] = __builtin_amdgcn_fdot2(R1.s0, W.h[0], acc[oi][3], false);
                acc[oi][3] = __builtin_amdgcn_fdot2(R1.s1, W.h[1], acc[oi][3], false);
                acc[oi][3] = fmaf(wv4, R1.cy, acc[oi][3]);
            }
            R0 = R1;
            if (ky < 4) R1 = packrow6(A, C);
        }

        union { _Float16 h[4]; uint2 u; } O;
#pragma unroll
        for (int oi = 0; oi < NOC; ++oi) {
            const float m = fmaxf(fmaxf(acc[oi][0], acc[oi][1]), fmaxf(acc[oi][2], acc[oi][3]));
            O.h[oi] = (_Float16)fmaxf(m, 0.f);
        }
#pragma unroll
        for (int oi = NOC; oi < 4; ++oi) O.h[oi] = (_Float16)0.f;
        *(uint2*)(H1CH + (py * 12 + px) * 8 + ocb) = O.u;
    }
}

__global__ __launch_bounds__(256, 4) void fused_model(
    const float* __restrict__ xg,
    const float* __restrict__ c1w, const float* __restrict__ c1b,
    const float* __restrict__ c2w, const float* __restrict__ c2b,
    const float* __restrict__ f1w, const float* __restrict__ f1b,
    const float* __restrict__ f2w, const float* __restrict__ f2b,
    const float* __restrict__ qw,  const float* __restrict__ cw,
    const float* __restrict__ cbias, float* __restrict__ out) {
    __shared__ float L[LDS_FLOATS];
    const int tid = threadIdx.x;
    const int b0 = blockIdx.x * 16;
    const int lane = tid & 63, wvi = tid >> 6;   // wvi 0..3
    const int ml = lane & 15, q = lane >> 4;

    _Float16* W2BH = (_Float16*)(L + W2B_F);
    _Float16* H2AH = (_Float16*)(L + H2A_F);
    _Float16* H1CH = (_Float16*)(L + PW_F) + wvi * H1_WV_H;
    _Float16* HSH  = (_Float16*)(L + PW_F);     // fc1 output overlay (PW dead)

    // ================= stage shared constants (one barrier) ================
    if (tid < 120) {  // conv1 weight f16 pairs
        const int oc = tid / 20, r = tid - oc * 20, ky = r >> 2, j = r & 3;
        const float* wb = c1w + oc * 25 + ky * 5;
        float lo, hi;
        if (j == 0)      { lo = wb[0]; hi = wb[1]; }
        else if (j == 1) { lo = wb[2]; hi = wb[3]; }
        else if (j == 2) { lo = wb[4]; hi = 0.f;   }
        else             { lo = 0.f;   hi = wb[4]; }
        ((h2*)&L[C1P_F])[tid] = __builtin_amdgcn_cvt_pkrtz(lo, hi);
    }
    if (tid < 6)  L[BS1_F + tid] = c1b[tid];
    if (tid < 16) L[BS2_F + tid] = c2b[tid];
    if (tid < 40) L[CWB_F + tid] = cw[tid];
    if (tid < 10) L[CWB_F + 40 + tid] = cbias[tid];
    if (tid < 12) {  // Rot gate matrices (batch-uniform)
        const float phi = qw[tid * 3 + 0];
        const float th  = qw[tid * 3 + 1];
        const float om  = qw[tid * 3 + 2];
        const float ct = cosf(0.5f * th), st = sinf(0.5f * th);
        const float ap = 0.5f * (phi + om), bm = 0.5f * (phi - om);
        const float ca = cosf(ap), sa = sinf(ap);
        const float cbm = cosf(bm), sbm = sinf(bm);
        float* R = &L[ROTM_F + tid * 8];
        R[0] =  ct * ca;  R[1] = -ct * sa;
        R[2] = -st * cbm; R[3] = -st * sbm;
        R[4] =  st * cbm; R[5] = -st * sbm;
        R[6] =  ct * ca;  R[7] =  ct * sa;
    }
#pragma unroll 1
    for (int i = tid; i < 3712; i += 256) {  // conv2 weights f16 [16][232]
        const int oc = i / 232, r = i - oc * 232;
        float v = 0.f;
        if (r < 200) {
            const int pix = r >> 3, ic = r & 7;
            if (ic < 6) v = c2w[oc * 150 + ic * 25 + pix];
        }
        W2BH[oc * 232 + r] = (_Float16)v;
    }
    __syncthreads();

    // ========== per-wave conv1+conv2, four samples sequentially ============
#pragma unroll 1
    for (int s = 0; s < 4; ++s) {
        const int smp = b0 + 4 * wvi + s;
        const float* xbase = xg + (size_t)smp * 784;

        conv1_pass<4>(0, xbase, c1w, (const h2*)&L[C1P_F], &L[BS1_F], H1CH, lane);
        conv1_pass<2>(4, xbase, c1w, (const h2*)&L[C1P_F], &L[BS1_F], H1CH, lane);
        __builtin_amdgcn_wave_barrier();

        // ---- conv2 via MFMA (b128 fragments) -> H2A row -----------------
        {
            f32x4 c2a[4];
#pragma unroll
            for (int b = 0; b < 4; b++) c2a[b] = (f32x4){0.f, 0.f, 0.f, 0.f};

#pragma unroll
            for (int ks = 0; ks < 7; ks++) {
                const half8 bfrag = *(const half8*)(W2BH + ml * 232 + ks * 32 + q * 8);
                int tp = ks * 4 + q; if (tp > 24) tp = 24;  // pad taps: B=0
                const int poff = (tp / 5) * 12 + (tp % 5);
#pragma unroll
                for (int t = 0; t < 4; t++) {
                    const int cp = t * 16 + ml;
                    const int unit = (cp >> 3) * 12 + (cp & 7) + poff;
                    const half8 afrag = *(const half8*)(H1CH + unit * 8);
                    c2a[t] = __builtin_amdgcn_mfma_f32_16x16x32_f16(afrag, bfrag, c2a[t], 0, 0, 0);
                }
            }

            // bias + pool + relu -> H2A row (4*wvi+s), own row: no race
            const float bv = L[BS2_F + ml];
#pragma unroll
            for (int t = 0; t < 4; t++) {
                const float c0 = c2a[t][0] + bv, c1 = c2a[t][1] + bv;
                const float c2 = c2a[t][2] + bv, c3 = c2a[t][3] + bv;
                float px0 = fmaxf(c0, c1), px1 = fmaxf(c2, c3);
                px0 = fmaxf(px0, __shfl_xor(px0, 32));
                px1 = fmaxf(px1, __shfl_xor(px1, 32));
                if (lane < 32) {
                    union { _Float16 h[2]; unsigned u; } P2;
                    P2.h[0] = (_Float16)fmaxf(px0, 0.f);
                    P2.h[1] = (_Float16)fmaxf(px1, 0.f);
                    *(unsigned*)(H2AH + (4 * wvi + s) * H2A_ROW_H + ml * 16 + t * 4 + (q & 1) * 2) = P2.u;
                }
            }
        }
        __builtin_amdgcn_wave_barrier();
    }
    __syncthreads();

    // ============ fc1 (256->120) via MFMA, M=16, 2 n-tiles per wave ========
    {
        f32x4 fcC[2];
        fcC[0] = (f32x4){0.f, 0.f, 0.f, 0.f};
        fcC[1] = (f32x4){0.f, 0.f, 0.f, 0.f};
        const _Float16* h2p = H2AH + ml * H2A_ROW_H;  // A: sample = ml
#pragma unroll
        for (int ks = 0; ks < 8; ks++) {
            const half8 afrag = *(const half8*)(h2p + ks * 32 + q * 8);
#pragma unroll
            for (int ti = 0; ti < 2; ti++) {
                const int n = (wvi + 4 * ti) * 16 + ml;
                half8 bfrag;
                if (n < 120) {
                    const float* wp = f1w + (size_t)n * 256 + ks * 32 + q * 8;
                    const float4 u = *(const float4*)wp;
                    const float4 v = *(const float4*)(wp + 4);
                    union { h2 p[4]; half8 h8; } B;
                    B.p[0] = __builtin_amdgcn_cvt_pkrtz(u.x, u.y);
                    B.p[1] = __builtin_amdgcn_cvt_pkrtz(u.z, u.w);
                    B.p[2] = __builtin_amdgcn_cvt_pkrtz(v.x, v.y);
                    B.p[3] = __builtin_amdgcn_cvt_pkrtz(v.z, v.w);
                    bfrag = B.h8;
                } else {
#pragma unroll
                    for (int j = 0; j < 8; j++) bfrag[j] = (_Float16)0.f;
                }
                fcC[ti] = __builtin_amdgcn_mfma_f32_16x16x32_f16(afrag, bfrag, fcC[ti], 0, 0, 0);
            }
        }
        // C: col=ml -> neuron n, row=q*4+rg -> sample
#pragma unroll
        for (int ti = 0; ti < 2; ti++) {
            const int n = (wvi + 4 * ti) * 16 + ml;
            if (n < 120) {
                const float bb = f1b[n];
#pragma unroll
                for (int rg = 0; rg < 4; rg++) {
                    const int sr = q * 4 + rg;
                    HSH[sr * HS_ROW_H + n] = (_Float16)fmaxf(fcC[ti][rg] + bb, 0.f);
                }
            }
        }
    }
    __syncthreads();

    // ====== fc2 (120->4) + pi*sigmoid, 256 threads (4-way split-K) =========
    {
        const int s = tid >> 4, m = (tid >> 2) & 3, part = tid & 3;
        float f = (part == 0) ? f2b[m] : 0.f;
#pragma unroll
        for (int i = 0; i < 4; ++i) {
            const int bblk = part + 4 * i;
            if (bblk < 15) {
                const half8 hv = *(const half8*)(HSH + s * HS_ROW_H + bblk * 8);
                const float* wp = f2w + m * 120 + bblk * 8;
                const float4 w0 = *(const float4*)wp;
                const float4 w1 = *(const float4*)(wp + 4);
                f = fmaf(w0.x, (float)hv[0], f); f = fmaf(w0.y, (float)hv[1], f);
                f = fmaf(w0.z, (float)hv[2], f); f = fmaf(w0.w, (float)hv[3], f);
                f = fmaf(w1.x, (float)hv[4], f); f = fmaf(w1.y, (float)hv[5], f);
                f = fmaf(w1.z, (float)hv[6], f); f = fmaf(w1.w, (float)hv[7], f);
            }
        }
        f += __shfl_xor(f, 1);
        f += __shfl_xor(f, 2);
        if (part == 0) {
            const float ang = 3.14159265358979323846f / (1.f + expf(-f));
            L[RXCS_F + s * 4 + m]      = cosf(0.5f * ang);
            L[RXCS_F + 64 + s * 4 + m] = sinf(0.5f * ang);
        }
    }
    __syncthreads();

    // ============ circuit: 16 samples x 16 amplitudes on 4 waves ===========
    {
        const int s = tid >> 4, a = tid & 15;
        float ar = (a == 0) ? 1.f : 0.f, ai = 0.f;

#pragma unroll
        for (int l = 0; l < 3; l++) {
#pragma unroll
            for (int w = 0; w < 4; w++) {
                const float* R = &L[ROTM_F + (l * 4 + w) * 8];
                const int mask = 8 >> w;
                const float pr = __shfl_xor(ar, mask);
                const float pi = __shfl_xor(ai, mask);
                const bool bit = (a & mask) != 0;
                const float lr = bit ? pr : ar, li = bit ? pi : ai;
                const float hr = bit ? ar : pr, hi = bit ? ai : pi;
                const float Ar = bit ? R[4] : R[0], Ai = bit ? R[5] : R[1];
                const float Br = bit ? R[6] : R[2], Bi = bit ? R[7] : R[3];
                ar = Ar * lr - Ai * li + Br * hr - Bi * hi;
                ai = Ar * li + Ai * lr + Br * hi + Bi * hr;
            }
#pragma unroll
            for (int w = 0; w < 4; w++) {
                const int mc = 8 >> w, mt = 8 >> ((w + 1) & 3);
                const float pr = __shfl_xor(ar, mt);
                const float pi = __shfl_xor(ai, mt);
                const bool ctrl = (a & mc) != 0;
                ar = ctrl ? pr : ar;
                ai = ctrl ? pi : ai;
            }
#pragma unroll
            for (int w = 0; w < 4; w++) {
                const int mask = 8 >> w;
                const float c  = L[RXCS_F + s * 4 + w];
                const float s2 = L[RXCS_F + 64 + s * 4 + w];
                const float pr = __shfl_xor(ar, mask);
                const float pi = __shfl_xor(ai, mask);
                const float nr = fmaf(c, ar, s2 * pi);
                const float ni = fmaf(c, ai, -s2 * pr);
                ar = nr; ai = ni;
            }
        }

        float v = ar * ar + ai * ai;
#pragma unroll
        for (int d = 1; d < 16; d <<= 1) {
            const float pv = __shfl_xor(v, d);
            v = (a & d) ? (pv - v) : (v + pv);
        }

        if (a < 10) {
            const int base = (tid & 63) & ~15;
            float lg = L[CWB_F + 40 + a];
#pragma unroll
            for (int w = 0; w < 4; w++) {
                const float zw = __shfl(v, base | (8 >> w));
                lg = fmaf(L[CWB_F + a * 4 + w], zw, lg);
            }
            out[(size_t)(b0 + s) * 10 + a] = lg;
        }
    }
}

// ---------------------------------------------------------------------------
extern "C" void kernel_launch(void* const* d_in, const int* in_sizes, int n_in,
                              void* d_out, int out_size, void* d_ws, size_t ws_size,
                              hipStream_t stream) {
    const float* x   = (const float*)d_in[0];
    const float* c1w = (const float*)d_in[1];
    const float* c1b = (const float*)d_in[2];
    const float* c2w = (const float*)d_in[3];
    const float* c2b = (const float*)d_in[4];
    const float* f1w = (const float*)d_in[5];
    const float* f1b = (const float*)d_in[6];
    const float* f2w = (const float*)d_in[7];
    const float* f2b = (const float*)d_in[8];
    const float* qw  = (const float*)d_in[9];
    const float* cw  = (const float*)d_in[10];
    const float* cb  = (const float*)d_in[11];
    float* out = (float*)d_out;

    fused_model<<<BATCH_N / 16, 256, 0, stream>>>(x, c1w, c1b, c2w, c2b,
                                                  f1w, f1b, f2w, f2b,
                                                  qw, cw, cb, out);
}